// Round 4
// baseline (1083.851 us; speedup 1.0000x reference)
//
#include <hip/hip_runtime.h>
#include <hip/hip_bf16.h>

// ---------------------------------------------------------------------------
// GCN variational encoder (mu, logvar) on MI355X — round 4.
//   h[n] = dinv[n] * ( xs[n] + sum_{s->n} xs[s] ),  xs = dinv*x  (self loop = xs[n])
//   mu = h@Wmu + bmu ; logvar = h@Wlv + blv
// R4: (1) xs cached in bf16 (halves gather traffic), (2) agg fused into the
// GEMM kernel (h lives only in LDS, no global round-trip, no alias hazard),
// (3) mu/lv split across waves so each thread holds one 64-reg W column set
// (VGPR<=128 -> 4 waves/SIMD; R3's 196 VGPR capped us at 2).
// ---------------------------------------------------------------------------

__device__ inline unsigned short f2bf(float f) {
    union { float f; unsigned u; } c; c.f = f;
    unsigned u = c.u;
    return (unsigned short)((u + 0x7FFFu + ((u >> 16) & 1u)) >> 16);  // RNE
}
__device__ inline float bf2f(unsigned short h) {
    union { unsigned u; float f; } c; c.u = ((unsigned)h) << 16;
    return c.f;
}

__global__ void k_zero(int* __restrict__ p, int n) {
    int i = blockIdx.x * blockDim.x + threadIdx.x;
    if (i < n) p[i] = 0;
}

__global__ void k_deg(const int* __restrict__ dst, int e, int* __restrict__ deg) {
    int i = blockIdx.x * blockDim.x + threadIdx.x;
    if (i < e) atomicAdd(&deg[dst[i]], 1);
}

// --- 3-kernel exclusive scan of deg[] -> start[] (and cursor, dinv) --------
__global__ void k_scan_block(const int* __restrict__ deg, int* __restrict__ start,
                             int* __restrict__ partial, int n) {
    __shared__ int sm[256];
    const int tid = threadIdx.x;
    const int i = blockIdx.x * 256 + tid;
    int v = (i < n) ? deg[i] : 0;
    sm[tid] = v;
    __syncthreads();
    for (int off = 1; off < 256; off <<= 1) {
        int t = (tid >= off) ? sm[tid - off] : 0;
        __syncthreads();
        sm[tid] += t;
        __syncthreads();
    }
    if (i < n) start[i] = sm[tid] - v;
    if (tid == 255) partial[blockIdx.x] = sm[255];
}

__global__ void k_scan_partial(int* __restrict__ partial, int nb) {
    __shared__ int sm[512];
    const int tid = threadIdx.x;
    int v = (tid < nb) ? partial[tid] : 0;
    sm[tid] = v;
    __syncthreads();
    for (int off = 1; off < 512; off <<= 1) {
        int t = (tid >= off) ? sm[tid - off] : 0;
        __syncthreads();
        sm[tid] += t;
        __syncthreads();
    }
    if (tid < nb) partial[tid] = sm[tid] - v;
}

__global__ void k_scan_add(int* __restrict__ start, int* __restrict__ cursor,
                           const int* __restrict__ partial, const int* __restrict__ deg,
                           float* __restrict__ dinv, int n) {
    int i = blockIdx.x * blockDim.x + threadIdx.x;
    if (i < n) {
        int s = start[i] + partial[i >> 8];
        start[i] = s;
        cursor[i] = s;
        dinv[i] = rsqrtf((float)(deg[i] + 1));   // +1 = self loop
    }
}

// xs = bf16(dinv[row] * x)  — 4 elems/thread
__global__ void k_xs(const float4* __restrict__ x4, const float* __restrict__ dinv,
                     ushort4* __restrict__ xs4, int n16) {
    int i = blockIdx.x * blockDim.x + threadIdx.x;
    if (i < n16) {
        float s = dinv[i >> 4];
        float4 v = x4[i];
        ushort4 o;
        o.x = f2bf(v.x * s); o.y = f2bf(v.y * s);
        o.z = f2bf(v.z * s); o.w = f2bf(v.w * s);
        xs4[i] = o;
    }
}

__global__ void k_sort(const int* __restrict__ src, const int* __restrict__ dst, int e,
                       int* __restrict__ cursor, int* __restrict__ srcSorted) {
    int i = blockIdx.x * blockDim.x + threadIdx.x;
    if (i < e) {
        int d = dst[i];
        int p = atomicAdd(&cursor[d], 1);
        srcSorted[p] = src[i];
    }
}

// --- fused aggregate + dual GEMM -------------------------------------------
// Per block: 64-node tile.
// Phase 1: 16-lane group per node-slot gathers bf16 xs rows (128B each,
//          16 lanes x 8B), accumulates in f32, writes h tile to LDS.
// Phase 2: waves 0-1 compute mu, waves 2-3 compute lv (each thread: one W
//          column set = 64 VGPR). 4-row ILP, h read as LDS float4 broadcast.
__global__ __launch_bounds__(256, 4) void k_fused(
        const ushort* __restrict__ xs, const float* __restrict__ dinv,
        const int* __restrict__ start, const int* __restrict__ deg,
        const int* __restrict__ srcS,
        const float* __restrict__ Wmu, const float* __restrict__ bmu,
        const float* __restrict__ Wlv, const float* __restrict__ blv,
        float* __restrict__ mu, float* __restrict__ lv, int n) {
    __shared__ float4 h4[64 * 16];                 // 16 KB
    const int tid = threadIdx.x;
    const int row0 = blockIdx.x * 64;

    // ---- phase 1: aggregation into LDS
    {
        const int g  = tid >> 4;                   // 0..15
        const int c4 = tid & 15;                   // float4 column
        for (int rr = g; rr < 64; rr += 16) {
            const int node = row0 + rr;
            float4 acc = make_float4(0.f, 0.f, 0.f, 0.f);
            if (node < n) {
                const int s0 = start[node];
                const int d  = deg[node];
                // self-loop term = xs[node]
                ushort4 v = *(const ushort4*)(xs + (((size_t)node) << 6) + (c4 << 2));
                acc.x = bf2f(v.x); acc.y = bf2f(v.y);
                acc.z = bf2f(v.z); acc.w = bf2f(v.w);
                int k = 0;
                for (; k + 2 <= d; k += 2) {
                    int s1 = srcS[s0 + k];
                    int s2 = srcS[s0 + k + 1];
                    ushort4 a = *(const ushort4*)(xs + (((size_t)s1) << 6) + (c4 << 2));
                    ushort4 b = *(const ushort4*)(xs + (((size_t)s2) << 6) + (c4 << 2));
                    acc.x += bf2f(a.x) + bf2f(b.x);
                    acc.y += bf2f(a.y) + bf2f(b.y);
                    acc.z += bf2f(a.z) + bf2f(b.z);
                    acc.w += bf2f(a.w) + bf2f(b.w);
                }
                if (k < d) {
                    int s1 = srcS[s0 + k];
                    ushort4 a = *(const ushort4*)(xs + (((size_t)s1) << 6) + (c4 << 2));
                    acc.x += bf2f(a.x); acc.y += bf2f(a.y);
                    acc.z += bf2f(a.z); acc.w += bf2f(a.w);
                }
                const float dn = dinv[node];
                acc.x *= dn; acc.y *= dn; acc.z *= dn; acc.w *= dn;
            }
            h4[rr * 16 + c4] = acc;                // zeros for tail rows
        }
    }

    // ---- W columns to registers (independent of phase 1, before barrier)
    const int j  = tid & 63;
    const int rg = tid >> 6;                       // wave id 0..3
    const float* __restrict__ W  = (rg & 2) ? Wlv : Wmu;
    const float* __restrict__ bb = (rg & 2) ? blv : bmu;
    float* __restrict__ outp     = (rg & 2) ? lv  : mu;
    float w_r[64];
    #pragma unroll
    for (int k = 0; k < 64; ++k) w_r[k] = W[k * 64 + j];   // coalesced 256B
    const float bj = bb[j];
    __syncthreads();

    // ---- phase 2: GEMM, each wave covers 32 rows (4-row ILP)
    const int rbase = (rg & 1) * 32;
    #pragma unroll
    for (int ib = 0; ib < 8; ++ib) {
        const int r0 = rbase + ib * 4;
        float a0 = bj, a1 = bj, a2 = bj, a3 = bj;
        #pragma unroll
        for (int kq = 0; kq < 16; ++kq) {
            float4 h0 = h4[(r0 + 0) * 16 + kq];    // wave-broadcast reads
            float4 h1 = h4[(r0 + 1) * 16 + kq];
            float4 h2 = h4[(r0 + 2) * 16 + kq];
            float4 h3 = h4[(r0 + 3) * 16 + kq];
            float w0 = w_r[4 * kq], w1 = w_r[4 * kq + 1];
            float w2 = w_r[4 * kq + 2], w3 = w_r[4 * kq + 3];
            a0 = fmaf(h0.x, w0, a0); a0 = fmaf(h0.y, w1, a0);
            a0 = fmaf(h0.z, w2, a0); a0 = fmaf(h0.w, w3, a0);
            a1 = fmaf(h1.x, w0, a1); a1 = fmaf(h1.y, w1, a1);
            a1 = fmaf(h1.z, w2, a1); a1 = fmaf(h1.w, w3, a1);
            a2 = fmaf(h2.x, w0, a2); a2 = fmaf(h2.y, w1, a2);
            a2 = fmaf(h2.z, w2, a2); a2 = fmaf(h2.w, w3, a2);
            a3 = fmaf(h3.x, w0, a3); a3 = fmaf(h3.y, w1, a3);
            a3 = fmaf(h3.z, w2, a3); a3 = fmaf(h3.w, w3, a3);
        }
        const int row = row0 + r0;
        if (row + 0 < n) outp[(size_t)(row + 0) * 64 + j] = a0;
        if (row + 1 < n) outp[(size_t)(row + 1) * 64 + j] = a1;
        if (row + 2 < n) outp[(size_t)(row + 2) * 64 + j] = a2;
        if (row + 3 < n) outp[(size_t)(row + 3) * 64 + j] = a3;
    }
}

extern "C" void kernel_launch(void* const* d_in, const int* in_sizes, int n_in,
                              void* d_out, int out_size, void* d_ws, size_t ws_size,
                              hipStream_t stream) {
    const float* x   = (const float*)d_in[0];
    const int* eidx  = (const int*)d_in[1];
    const float* Wmu = (const float*)d_in[2];
    const float* bmu = (const float*)d_in[3];
    const float* Wlv = (const float*)d_in[4];
    const float* blv = (const float*)d_in[5];

    const int N = in_sizes[0] / 64;
    const int E = in_sizes[1] / 2;
    const int* src = eidx;
    const int* dst = eidx + E;

    // ws: deg dinv start cursor partial xs(bf16) srcSorted  (~19.3 MB)
    char* ws = (char*)d_ws;
    size_t off = 0;
    int*    deg    = (int*)(ws + off);    off += ((size_t)N * 4 + 255) & ~(size_t)255;
    float*  dinv   = (float*)(ws + off);  off += ((size_t)N * 4 + 255) & ~(size_t)255;
    int*    start  = (int*)(ws + off);    off += ((size_t)N * 4 + 255) & ~(size_t)255;
    int*    cursor = (int*)(ws + off);    off += ((size_t)N * 4 + 255) & ~(size_t)255;
    int*    partial= (int*)(ws + off);    off += 2048;
    ushort* xsb    = (ushort*)(ws + off); off += ((size_t)N * 64 * 2 + 255) & ~(size_t)255;
    int*    srcS   = (int*)(ws + off);    off += ((size_t)E * 4 + 255) & ~(size_t)255;

    float* mu = (float*)d_out;
    float* lv = mu + (size_t)N * 64;

    const int B = 256;
    const int nb = (N + 255) / 256;        // 391 <= 512

    k_zero<<<(N + B - 1) / B, B, 0, stream>>>(deg, N);
    k_deg<<<(E + B - 1) / B, B, 0, stream>>>(dst, E, deg);

    k_scan_block<<<nb, 256, 0, stream>>>(deg, start, partial, N);
    k_scan_partial<<<1, 512, 0, stream>>>(partial, nb);
    k_scan_add<<<(N + B - 1) / B, B, 0, stream>>>(start, cursor, partial, deg, dinv, N);

    k_xs<<<(N * 16 + B - 1) / B, B, 0, stream>>>((const float4*)x, dinv, (ushort4*)xsb, N * 16);
    k_sort<<<(E + B - 1) / B, B, 0, stream>>>(src, dst, E, cursor, srcS);

    k_fused<<<(N + 63) / 64, 256, 0, stream>>>(xsb, dinv, start, deg, srcS,
                                               Wmu, bmu, Wlv, blv, mu, lv, N);
}

// Round 6
// 298.876 us; speedup vs baseline: 3.6264x; 3.6264x over previous
//
#include <hip/hip_runtime.h>

// ---------------------------------------------------------------------------
// GCN variational encoder (mu, logvar) on MI355X — round 6.
//   h[n] = dinv[n] * ( xs[n] + sum_{s->n} xs[s] ),  xs = bf16(dinv*x)
//   mu = h@Wmu + bmu ; logvar = h@Wlv + blv
// R6 fix: R5 packed bf16 h densely in the lv half of d_out; block b's lv
// writes (256B/row) clobbered hb rows of OTHER blocks (128B/row) -> race ->
// NaN. Now h is parked TILED: tile b's 8KB of h lives at byte b*16384, i.e.
// inside block b's own 16KB lv output slice. Cross-block disjoint; within a
// block, h is staged to LDS before the lv writes. No extra workspace.
// ---------------------------------------------------------------------------

typedef unsigned short u16;

__device__ inline u16 f2bf(float f) {
    union { float f; unsigned u; } c; c.f = f;
    unsigned u = c.u;
    return (u16)((u + 0x7FFFu + ((u >> 16) & 1u)) >> 16);  // RNE
}
__device__ inline float bf2f(u16 h) {
    union { unsigned u; float f; } c; c.u = ((unsigned)h) << 16;
    return c.f;
}

__global__ void k_zero(int* __restrict__ p, int n) {
    int i = blockIdx.x * blockDim.x + threadIdx.x;
    if (i < n) p[i] = 0;
}

__global__ void k_deg(const int* __restrict__ dst, int e, int* __restrict__ deg) {
    int i = blockIdx.x * blockDim.x + threadIdx.x;
    if (i < e) atomicAdd(&deg[dst[i]], 1);
}

// --- 3-kernel exclusive scan of deg[] -> start[], cursor[], plus dinv ------
__global__ void k_scan_block(const int* __restrict__ deg, int* __restrict__ start,
                             int* __restrict__ partial, int n) {
    __shared__ int sm[256];
    const int tid = threadIdx.x;
    const int i = blockIdx.x * 256 + tid;
    int v = (i < n) ? deg[i] : 0;
    sm[tid] = v;
    __syncthreads();
    for (int off = 1; off < 256; off <<= 1) {
        int t = (tid >= off) ? sm[tid - off] : 0;
        __syncthreads();
        sm[tid] += t;
        __syncthreads();
    }
    if (i < n) start[i] = sm[tid] - v;
    if (tid == 255) partial[blockIdx.x] = sm[255];
}

__global__ void k_scan_partial(int* __restrict__ partial, int nb) {
    __shared__ int sm[512];
    const int tid = threadIdx.x;
    int v = (tid < nb) ? partial[tid] : 0;
    sm[tid] = v;
    __syncthreads();
    for (int off = 1; off < 512; off <<= 1) {
        int t = (tid >= off) ? sm[tid - off] : 0;
        __syncthreads();
        sm[tid] += t;
        __syncthreads();
    }
    if (tid < nb) partial[tid] = sm[tid] - v;
}

__global__ void k_scan_add(int* __restrict__ start, int* __restrict__ cursor,
                           const int* __restrict__ partial, const int* __restrict__ deg,
                           float* __restrict__ dinv, int n) {
    int i = blockIdx.x * blockDim.x + threadIdx.x;
    if (i < n) {
        int s = start[i] + partial[i >> 8];
        start[i] = s;
        cursor[i] = s;
        dinv[i] = rsqrtf((float)(deg[i] + 1));   // +1 = self loop
    }
}

// xs = bf16(dinv[row] * x)  — 4 elems/thread
__global__ void k_xs(const float4* __restrict__ x4, const float* __restrict__ dinv,
                     ushort4* __restrict__ xs4, int n16) {
    int i = blockIdx.x * blockDim.x + threadIdx.x;
    if (i < n16) {
        float s = dinv[i >> 4];
        float4 v = x4[i];
        ushort4 o;
        o.x = f2bf(v.x * s); o.y = f2bf(v.y * s);
        o.z = f2bf(v.z * s); o.w = f2bf(v.w * s);
        xs4[i] = o;
    }
}

__global__ void k_sort(const int* __restrict__ src, const int* __restrict__ dst, int e,
                       int* __restrict__ cursor, int* __restrict__ srcSorted) {
    int i = blockIdx.x * blockDim.x + threadIdx.x;
    if (i < e) {
        int d = dst[i];
        int p = atomicAdd(&cursor[d], 1);
        srcSorted[p] = src[i];
    }
}

// --- gather aggregation: one wave per node, 4 bf16 rows per iteration ------
// lane = sub*16 + c4: group `sub` handles edges k = sub, sub+4, ...;
// 16 lanes load the 128B bf16 row as ushort4. f32 accumulate, 2 shfl_xor
// rounds reduce the 4 partials. h written bf16 into the TILED slot:
// u16 index tile*8192 + r*64 + col  (tile = node>>6, r = node&63).
__global__ __launch_bounds__(256) void k_agg(
        const u16* __restrict__ xs, const float* __restrict__ dinv,
        const int* __restrict__ start, const int* __restrict__ deg,
        const int* __restrict__ srcS, u16* __restrict__ hb, int n) {
    const int lane = threadIdx.x & 63;
    const int node = blockIdx.x * 4 + (threadIdx.x >> 6);
    if (node >= n) return;
    const int sub = lane >> 4;
    const int c4  = lane & 15;
    const int s0 = start[node];
    const int d  = deg[node];

    float4 acc = make_float4(0.f, 0.f, 0.f, 0.f);
    for (int k = sub; k < d; k += 4) {
        int s = srcS[s0 + k];                       // broadcast in 16-group
        ushort4 v = *(const ushort4*)(xs + (((size_t)s) << 6) + (c4 << 2));
        acc.x += bf2f(v.x); acc.y += bf2f(v.y);
        acc.z += bf2f(v.z); acc.w += bf2f(v.w);
    }
    acc.x += __shfl_xor(acc.x, 16); acc.x += __shfl_xor(acc.x, 32);
    acc.y += __shfl_xor(acc.y, 16); acc.y += __shfl_xor(acc.y, 32);
    acc.z += __shfl_xor(acc.z, 16); acc.z += __shfl_xor(acc.z, 32);
    acc.w += __shfl_xor(acc.w, 16); acc.w += __shfl_xor(acc.w, 32);

    if (sub == 0) {
        ushort4 v = *(const ushort4*)(xs + (((size_t)node) << 6) + (c4 << 2));
        const float dn = dinv[node];
        ushort4 o;
        o.x = f2bf(dn * (acc.x + bf2f(v.x)));       // + self loop, * dinv[dst]
        o.y = f2bf(dn * (acc.y + bf2f(v.y)));
        o.z = f2bf(dn * (acc.z + bf2f(v.z)));
        o.w = f2bf(dn * (acc.w + bf2f(v.w)));
        const size_t tile = (size_t)(node >> 6);
        const int r = node & 63;
        *(ushort4*)(hb + tile * 8192 + r * 64 + (c4 << 2)) = o;
    }
}

// --- dual GEMM: waves 0-1 -> mu, waves 2-3 -> lv ---------------------------
// h tile (bf16, tiled layout inside block's own lv slice) staged to LDS as
// f32; W columns in registers (single 64-reg set per thread); 4-row ILP.
// All hb reads complete before the barrier; lv writes after -> no hazard.
__global__ __launch_bounds__(256) void k_gemm2(
        const u16* __restrict__ hb,
        const float* __restrict__ Wmu, const float* __restrict__ bmu,
        const float* __restrict__ Wlv, const float* __restrict__ blv,
        float* __restrict__ mu, float* __restrict__ lv, int n) {
    __shared__ float4 h4[64 * 16];                  // 16 KB
    const int tid = threadIdx.x;
    const int row0 = blockIdx.x * 64;
    const size_t tbase = (size_t)blockIdx.x * 8192; // u16 units (16KB lv slice)

    for (int t = tid; t < 1024; t += 256) {
        int r = t >> 4, c = t & 15;
        int row = row0 + r;
        float4 f = make_float4(0.f, 0.f, 0.f, 0.f);
        if (row < n) {
            ushort4 v = *(const ushort4*)(hb + tbase + r * 64 + (c << 2));
            f.x = bf2f(v.x); f.y = bf2f(v.y); f.z = bf2f(v.z); f.w = bf2f(v.w);
        }
        h4[r * 16 + c] = f;
    }

    const int j  = tid & 63;
    const int rg = tid >> 6;
    const float* __restrict__ W  = (rg & 2) ? Wlv : Wmu;
    const float* __restrict__ bb = (rg & 2) ? blv : bmu;
    float* __restrict__ outp     = (rg & 2) ? lv  : mu;
    float w_r[64];
    #pragma unroll
    for (int k = 0; k < 64; ++k) w_r[k] = W[k * 64 + j];   // coalesced
    const float bj = bb[j];
    __syncthreads();

    const int rbase = (rg & 1) * 32;
    #pragma unroll
    for (int ib = 0; ib < 8; ++ib) {
        const int r0 = rbase + ib * 4;
        float a0 = bj, a1 = bj, a2 = bj, a3 = bj;
        #pragma unroll
        for (int kq = 0; kq < 16; ++kq) {
            float4 h0 = h4[(r0 + 0) * 16 + kq];     // wave-broadcast reads
            float4 h1 = h4[(r0 + 1) * 16 + kq];
            float4 h2 = h4[(r0 + 2) * 16 + kq];
            float4 h3 = h4[(r0 + 3) * 16 + kq];
            float w0 = w_r[4 * kq], w1 = w_r[4 * kq + 1];
            float w2 = w_r[4 * kq + 2], w3 = w_r[4 * kq + 3];
            a0 = fmaf(h0.x, w0, a0); a0 = fmaf(h0.y, w1, a0);
            a0 = fmaf(h0.z, w2, a0); a0 = fmaf(h0.w, w3, a0);
            a1 = fmaf(h1.x, w0, a1); a1 = fmaf(h1.y, w1, a1);
            a1 = fmaf(h1.z, w2, a1); a1 = fmaf(h1.w, w3, a1);
            a2 = fmaf(h2.x, w0, a2); a2 = fmaf(h2.y, w1, a2);
            a2 = fmaf(h2.z, w2, a2); a2 = fmaf(h2.w, w3, a2);
            a3 = fmaf(h3.x, w0, a3); a3 = fmaf(h3.y, w1, a3);
            a3 = fmaf(h3.z, w2, a3); a3 = fmaf(h3.w, w3, a3);
        }
        const int row = row0 + r0;
        if (row + 0 < n) outp[(size_t)(row + 0) * 64 + j] = a0;
        if (row + 1 < n) outp[(size_t)(row + 1) * 64 + j] = a1;
        if (row + 2 < n) outp[(size_t)(row + 2) * 64 + j] = a2;
        if (row + 3 < n) outp[(size_t)(row + 3) * 64 + j] = a3;
    }
}

extern "C" void kernel_launch(void* const* d_in, const int* in_sizes, int n_in,
                              void* d_out, int out_size, void* d_ws, size_t ws_size,
                              hipStream_t stream) {
    const float* x   = (const float*)d_in[0];
    const int* eidx  = (const int*)d_in[1];
    const float* Wmu = (const float*)d_in[2];
    const float* bmu = (const float*)d_in[3];
    const float* Wlv = (const float*)d_in[4];
    const float* blv = (const float*)d_in[5];

    const int N = in_sizes[0] / 64;
    const int E = in_sizes[1] / 2;
    const int* src = eidx;
    const int* dst = eidx + E;

    // ws: deg dinv start cursor partial xs(bf16) srcSorted  (~19.3 MB)
    char* ws = (char*)d_ws;
    size_t off = 0;
    int*   deg    = (int*)(ws + off);    off += ((size_t)N * 4 + 255) & ~(size_t)255;
    float* dinv   = (float*)(ws + off);  off += ((size_t)N * 4 + 255) & ~(size_t)255;
    int*   start  = (int*)(ws + off);    off += ((size_t)N * 4 + 255) & ~(size_t)255;
    int*   cursor = (int*)(ws + off);    off += ((size_t)N * 4 + 255) & ~(size_t)255;
    int*   partial= (int*)(ws + off);    off += 2048;
    u16*   xsb    = (u16*)(ws + off);    off += ((size_t)N * 64 * 2 + 255) & ~(size_t)255;
    int*   srcS   = (int*)(ws + off);    off += ((size_t)E * 4 + 255) & ~(size_t)255;

    float* mu = (float*)d_out;
    float* lv = mu + (size_t)N * 64;
    u16*   hb = (u16*)lv;                  // bf16 h, TILED inside lv slices

    const int B = 256;
    const int nb = (N + 255) / 256;        // 391 <= 512

    k_zero<<<(N + B - 1) / B, B, 0, stream>>>(deg, N);
    k_deg<<<(E + B - 1) / B, B, 0, stream>>>(dst, E, deg);

    k_scan_block<<<nb, 256, 0, stream>>>(deg, start, partial, N);
    k_scan_partial<<<1, 512, 0, stream>>>(partial, nb);
    k_scan_add<<<(N + B - 1) / B, B, 0, stream>>>(start, cursor, partial, deg, dinv, N);

    k_xs<<<(N * 16 + B - 1) / B, B, 0, stream>>>((const float4*)x, dinv, (ushort4*)xsb, N * 16);
    k_sort<<<(E + B - 1) / B, B, 0, stream>>>(src, dst, E, cursor, srcS);

    k_agg<<<(N + 3) / 4, 256, 0, stream>>>(xsb, dinv, start, deg, srcS, hb, N);

    k_gemm2<<<(N + 63) / 64, 256, 0, stream>>>(hb, Wmu, bmu, Wlv, blv, mu, lv, N);
}

// Round 7
// 217.398 us; speedup vs baseline: 4.9856x; 1.3748x over previous
//
#include <hip/hip_runtime.h>

// ---------------------------------------------------------------------------
// GCN variational encoder (mu, logvar) on MI355X — round 7.
//   h[n] = dinv[n] * ( xs[n] + sum_{s->n} xs[s] ),  xs = bf16(dinv*x)
//   mu = h@Wmu + bmu ; logvar = h@Wlv + blv
// R7: (1) GEMM on the MATRIX pipe: mfma_f32_16x16x32_bf16, W pre-converted
// to bf16 transposed (WbT[mat][n][k]); VALU version was stuck at 103us /
// 29% VALUBusy across 4 rounds (LDS-broadcast + dep-latency bound).
// (2) k_agg gathers 8 edges/iter (8 subgroups x 8 lanes x 16B = full row),
// halving memory instrs and serial depth.
// hb (bf16 h) stays TILED inside each block's own lv output slice.
// ---------------------------------------------------------------------------

typedef unsigned short u16;
typedef __attribute__((ext_vector_type(8))) short short8;   // 8 bf16 (4 VGPR)
typedef __attribute__((ext_vector_type(4))) float f32x4;

__device__ inline u16 f2bf(float f) {
    union { float f; unsigned u; } c; c.f = f;
    unsigned u = c.u;
    return (u16)((u + 0x7FFFu + ((u >> 16) & 1u)) >> 16);  // RNE
}
__device__ inline float bf2f(u16 h) {
    union { unsigned u; float f; } c; c.u = ((unsigned)h) << 16;
    return c.f;
}
__device__ inline float bfLo(unsigned u) {   // low u16 of packed pair
    union { unsigned u; float f; } c; c.u = u << 16; return c.f;
}
__device__ inline float bfHi(unsigned u) {   // high u16 of packed pair
    union { unsigned u; float f; } c; c.u = u & 0xFFFF0000u; return c.f;
}
__device__ inline unsigned packbf(float lo, float hi) {
    return ((unsigned)f2bf(hi) << 16) | (unsigned)f2bf(lo);
}

__global__ void k_zero(int* __restrict__ p, int n) {
    int i = blockIdx.x * blockDim.x + threadIdx.x;
    if (i < n) p[i] = 0;
}

__global__ void k_deg(const int* __restrict__ dst, int e, int* __restrict__ deg) {
    int i = blockIdx.x * blockDim.x + threadIdx.x;
    if (i < e) atomicAdd(&deg[dst[i]], 1);
}

// --- 3-kernel exclusive scan of deg[] -> start[], cursor[], plus dinv ------
__global__ void k_scan_block(const int* __restrict__ deg, int* __restrict__ start,
                             int* __restrict__ partial, int n) {
    __shared__ int sm[256];
    const int tid = threadIdx.x;
    const int i = blockIdx.x * 256 + tid;
    int v = (i < n) ? deg[i] : 0;
    sm[tid] = v;
    __syncthreads();
    for (int off = 1; off < 256; off <<= 1) {
        int t = (tid >= off) ? sm[tid - off] : 0;
        __syncthreads();
        sm[tid] += t;
        __syncthreads();
    }
    if (i < n) start[i] = sm[tid] - v;
    if (tid == 255) partial[blockIdx.x] = sm[255];
}

__global__ void k_scan_partial(int* __restrict__ partial, int nb) {
    __shared__ int sm[512];
    const int tid = threadIdx.x;
    int v = (tid < nb) ? partial[tid] : 0;
    sm[tid] = v;
    __syncthreads();
    for (int off = 1; off < 512; off <<= 1) {
        int t = (tid >= off) ? sm[tid - off] : 0;
        __syncthreads();
        sm[tid] += t;
        __syncthreads();
    }
    if (tid < nb) partial[tid] = sm[tid] - v;
}

__global__ void k_scan_add(int* __restrict__ start, int* __restrict__ cursor,
                           const int* __restrict__ partial, const int* __restrict__ deg,
                           float* __restrict__ dinv, int n) {
    int i = blockIdx.x * blockDim.x + threadIdx.x;
    if (i < n) {
        int s = start[i] + partial[i >> 8];
        start[i] = s;
        cursor[i] = s;
        dinv[i] = rsqrtf((float)(deg[i] + 1));   // +1 = self loop
    }
}

// xs = bf16(dinv[row] * x)
__global__ void k_xs(const float4* __restrict__ x4, const float* __restrict__ dinv,
                     ushort4* __restrict__ xs4, int n16) {
    int i = blockIdx.x * blockDim.x + threadIdx.x;
    if (i < n16) {
        float s = dinv[i >> 4];
        float4 v = x4[i];
        ushort4 o;
        o.x = f2bf(v.x * s); o.y = f2bf(v.y * s);
        o.z = f2bf(v.z * s); o.w = f2bf(v.w * s);
        xs4[i] = o;
    }
}

// WbT[mat][n][k] = bf16(W_mat[k][n]) — 8192 elements total
__global__ void k_wbt(const float* __restrict__ Wmu, const float* __restrict__ Wlv,
                      u16* __restrict__ WbT) {
    int t = blockIdx.x * blockDim.x + threadIdx.x;
    if (t < 8192) {
        int mat = t >> 12;
        int n = (t >> 6) & 63;
        int k = t & 63;
        const float* W = mat ? Wlv : Wmu;
        WbT[t] = f2bf(W[k * 64 + n]);
    }
}

__global__ void k_sort(const int* __restrict__ src, const int* __restrict__ dst, int e,
                       int* __restrict__ cursor, int* __restrict__ srcSorted) {
    int i = blockIdx.x * blockDim.x + threadIdx.x;
    if (i < e) {
        int d = dst[i];
        int p = atomicAdd(&cursor[d], 1);
        srcSorted[p] = src[i];
    }
}

// --- gather aggregation: one wave per node, 8 edges per iteration ----------
// lane = sub*8 + c8: subgroup `sub` (8 lanes x 16B = full 128B bf16 row)
// handles edges k = sub, sub+8, ... -> 8 independent load chains.
// 3 shfl_xor rounds (^8,^16,^32) reduce; lanes 0-7 add self-loop, scale by
// dinv[dst], write bf16 h into the TILED slot (tile*8192 + r*64 + col u16).
__global__ __launch_bounds__(256) void k_agg(
        const u16* __restrict__ xs, const float* __restrict__ dinv,
        const int* __restrict__ start, const int* __restrict__ deg,
        const int* __restrict__ srcS, u16* __restrict__ hb, int n) {
    const int lane = threadIdx.x & 63;
    const int node = blockIdx.x * 4 + (threadIdx.x >> 6);
    if (node >= n) return;
    const int sub = lane >> 3;
    const int c8  = lane & 7;                  // 16B chunk within row
    const int s0 = start[node];
    const int d  = deg[node];

    float a0=0.f,a1=0.f,a2=0.f,a3=0.f,a4=0.f,a5=0.f,a6=0.f,a7=0.f;
    for (int k = sub; k < d; k += 8) {
        int s = srcS[s0 + k];                  // uniform within 8-lane group
        uint4 v = *(const uint4*)(xs + (((size_t)s) << 6) + (c8 << 3));
        a0 += bfLo(v.x); a1 += bfHi(v.x);
        a2 += bfLo(v.y); a3 += bfHi(v.y);
        a4 += bfLo(v.z); a5 += bfHi(v.z);
        a6 += bfLo(v.w); a7 += bfHi(v.w);
    }
#define RED3(a) a += __shfl_xor(a, 8); a += __shfl_xor(a, 16); a += __shfl_xor(a, 32)
    RED3(a0); RED3(a1); RED3(a2); RED3(a3);
    RED3(a4); RED3(a5); RED3(a6); RED3(a7);
#undef RED3

    if (sub == 0) {
        uint4 v = *(const uint4*)(xs + (((size_t)node) << 6) + (c8 << 3));
        const float dn = dinv[node];
        float r0 = dn * (a0 + bfLo(v.x)), r1 = dn * (a1 + bfHi(v.x));
        float r2 = dn * (a2 + bfLo(v.y)), r3 = dn * (a3 + bfHi(v.y));
        float r4 = dn * (a4 + bfLo(v.z)), r5 = dn * (a5 + bfHi(v.z));
        float r6 = dn * (a6 + bfLo(v.w)), r7 = dn * (a7 + bfHi(v.w));
        uint4 o;
        o.x = packbf(r0, r1); o.y = packbf(r2, r3);
        o.z = packbf(r4, r5); o.w = packbf(r6, r7);
        *(uint4*)(hb + (size_t)(node >> 6) * 8192 + (node & 63) * 64 + (c8 << 3)) = o;
    }
}

// --- MFMA dual GEMM ---------------------------------------------------------
// Block = 4 waves, 64-row tile. Wave w owns rows row0+w*16..+15.
// A-frags (h, bf16) loaded direct from tiled hb: lane l -> row m=l&15,
// k = kh*32 + (l>>4)*8 + i (16B contiguous per lane).
// B-frags from WbT[mat][n][k]: n = ct*16 + (l&15), same k pattern.
// D: col = l&15 (+ct*16), row = (l>>4)*4 + reg (m89-verified layout).
// __syncthreads() between hb loads and lv stores (hb aliases lv slices).
__global__ __launch_bounds__(256) void k_gemm2(
        const u16* __restrict__ hb, const u16* __restrict__ WbT,
        const float* __restrict__ bmu, const float* __restrict__ blv,
        float* __restrict__ mu, float* __restrict__ lv, int n) {
    const int tid  = threadIdx.x;
    const int lane = tid & 63;
    const int w    = tid >> 6;          // wave 0..3
    const int row0 = blockIdx.x * 64;
    const int m    = lane & 15;
    const int kg   = lane >> 4;         // 0..3

    // A frags: two K-halves of this lane's h row slice
    const u16* hrow = hb + (size_t)blockIdx.x * 8192 + (size_t)(w * 16 + m) * 64 + kg * 8;
    short8 aF0 = *(const short8*)(hrow);
    short8 aF1 = *(const short8*)(hrow + 32);

    // B frags: all 16 (2 mats x 4 col-tiles x 2 K-halves), 64 VGPR
    short8 bF[2][4][2];
    #pragma unroll
    for (int mat = 0; mat < 2; ++mat)
        #pragma unroll
        for (int ct = 0; ct < 4; ++ct)
            #pragma unroll
            for (int kh = 0; kh < 2; ++kh)
                bF[mat][ct][kh] = *(const short8*)(
                    WbT + mat * 4096 + (ct * 16 + m) * 64 + kh * 32 + kg * 8);

    __syncthreads();   // drain hb reads before any wave's lv stores

    #pragma unroll
    for (int mat = 0; mat < 2; ++mat) {
        const float* __restrict__ bias = mat ? blv : bmu;
        float* __restrict__ outp       = mat ? lv  : mu;
        #pragma unroll
        for (int ct = 0; ct < 4; ++ct) {
            const float bj = bias[ct * 16 + m];
            f32x4 acc = {bj, bj, bj, bj};
            acc = __builtin_amdgcn_mfma_f32_16x16x32_bf16(aF0, bF[mat][ct][0], acc, 0, 0, 0);
            acc = __builtin_amdgcn_mfma_f32_16x16x32_bf16(aF1, bF[mat][ct][1], acc, 0, 0, 0);
            #pragma unroll
            for (int i = 0; i < 4; ++i) {
                const int row = row0 + w * 16 + kg * 4 + i;
                if (row < n) outp[(size_t)row * 64 + ct * 16 + m] = acc[i];
            }
        }
    }
}

extern "C" void kernel_launch(void* const* d_in, const int* in_sizes, int n_in,
                              void* d_out, int out_size, void* d_ws, size_t ws_size,
                              hipStream_t stream) {
    const float* x   = (const float*)d_in[0];
    const int* eidx  = (const int*)d_in[1];
    const float* Wmu = (const float*)d_in[2];
    const float* bmu = (const float*)d_in[3];
    const float* Wlv = (const float*)d_in[4];
    const float* blv = (const float*)d_in[5];

    const int N = in_sizes[0] / 64;
    const int E = in_sizes[1] / 2;
    const int* src = eidx;
    const int* dst = eidx + E;

    // ws: deg dinv start cursor partial WbT xs(bf16) srcSorted  (~19.3 MB)
    char* ws = (char*)d_ws;
    size_t off = 0;
    int*   deg    = (int*)(ws + off);    off += ((size_t)N * 4 + 255) & ~(size_t)255;
    float* dinv   = (float*)(ws + off);  off += ((size_t)N * 4 + 255) & ~(size_t)255;
    int*   start  = (int*)(ws + off);    off += ((size_t)N * 4 + 255) & ~(size_t)255;
    int*   cursor = (int*)(ws + off);    off += ((size_t)N * 4 + 255) & ~(size_t)255;
    int*   partial= (int*)(ws + off);    off += 2048;
    u16*   WbT    = (u16*)(ws + off);    off += 8192 * 2;
    u16*   xsb    = (u16*)(ws + off);    off += ((size_t)N * 64 * 2 + 255) & ~(size_t)255;
    int*   srcS   = (int*)(ws + off);    off += ((size_t)E * 4 + 255) & ~(size_t)255;

    float* mu = (float*)d_out;
    float* lv = mu + (size_t)N * 64;
    u16*   hb = (u16*)lv;                  // bf16 h, TILED inside lv slices

    const int B = 256;
    const int nb = (N + 255) / 256;        // 391 <= 512

    k_zero<<<(N + B - 1) / B, B, 0, stream>>>(deg, N);
    k_deg<<<(E + B - 1) / B, B, 0, stream>>>(dst, E, deg);
    k_wbt<<<32, 256, 0, stream>>>(Wmu, Wlv, WbT);

    k_scan_block<<<nb, 256, 0, stream>>>(deg, start, partial, N);
    k_scan_partial<<<1, 512, 0, stream>>>(partial, nb);
    k_scan_add<<<(N + B - 1) / B, B, 0, stream>>>(start, cursor, partial, deg, dinv, N);

    k_xs<<<(N * 16 + B - 1) / B, B, 0, stream>>>((const float4*)x, dinv, (ushort4*)xsb, N * 16);
    k_sort<<<(E + B - 1) / B, B, 0, stream>>>(src, dst, E, cursor, srcS);

    k_agg<<<(N + 3) / 4, 256, 0, stream>>>(xsb, dinv, start, deg, srcS, hb, N);

    k_gemm2<<<(N + 63) / 64, 256, 0, stream>>>(hb, WbT, bmu, blv, mu, lv, N);
}